// Round 1
// baseline (321.586 us; speedup 1.0000x reference)
//
#include <hip/hip_runtime.h>
#include <cstdint>

typedef __attribute__((ext_vector_type(8))) short bf16x8;
typedef __attribute__((ext_vector_type(4))) float f32x4;

__device__ __forceinline__ unsigned short f2bf(float v) {
  unsigned u = __builtin_bit_cast(unsigned, v);
  u += 0x7FFFu + ((u >> 16) & 1u);   // RNE
  return (unsigned short)(u >> 16);
}

// async global->LDS, 16B per lane; LDS dest = wave-uniform base + lane*16
__device__ __forceinline__ void gload16(const unsigned short* g, unsigned short* l) {
  __builtin_amdgcn_global_load_lds(
      (const __attribute__((address_space(1))) void*)(uintptr_t)g,
      (__attribute__((address_space(3))) void*)(uint32_t)(uintptr_t)l,
      16, 0, 0);
}

// raw barrier (NO implicit vmcnt(0) drain, unlike __syncthreads) + counted waits
#define BAR()   asm volatile("s_barrier" ::: "memory")
#define LGKM0() asm volatile("s_waitcnt lgkmcnt(0)" ::: "memory")
#define VM4()   asm volatile("s_waitcnt vmcnt(4)" ::: "memory")
#define VM0()   asm volatile("s_waitcnt vmcnt(0)" ::: "memory")

// Deep-pipelined bf16 NT GEMM core: C[128x256] += A[128xK] * B[256xK]^T, BK=64.
// 512 threads = 8 waves (2M x 4N), per-wave 64x64 output (acc[4][4]).
//
// LDS: ring of 6 units x 16 KiB (96 KiB). Unit = 128 rows x 64 shorts,
// XOR-swizzled 16B chunks (chunk c of row r at physical c^(r&7)) -> 0 bank
// conflicts on ds_read_b128, staging stays lane-contiguous for global_load_lds
// (source address pre-swizzled). Unit stream per K-tile t:
//   unit 3t+0 = B rows 0..127, 3t+1 = B rows 128..255, 3t+2 = A rows 0..127
// slot(u) = u mod 6.
//
// Schedule (T3+T4+T5): 2 phases per K-tile, 16 MFMA/phase/wave:
//  ph1: ds_read all B (8xb128) + A frags 0,1 (4xb128); stage A(t+1);
//       BAR; lgkm0; prio1; 16 MFMA; prio0; BAR
//  ph2: ds_read A frags 2,3 (4xb128); stage Blo/Bhi(t+2);
//       BAR; lgkm0; prio1; 16 MFMA; prio0; vmcnt(4|0); BAR
// Boundary vmcnt(4): <=2 units (4 loads) in flight -> tile t fully landed
// before its ph1 reads; vmcnt never drains to 0 until the last tile.
// Hazard-freedom: each slot's overwrite is issued >=1 double-barriered phase
// after its last read (B(t) last read ph1, overwritten by B(t+2) staged ph2;
// A(t) last read ph2, overwritten by A(t+2) staged ph1 of tile t+1).
__device__ __forceinline__ void gemm_core(
    const unsigned short* __restrict__ A, const unsigned short* __restrict__ B,
    int lda, int ldb, int NT,
    unsigned short* lds, f32x4 acc[4][4])
{
  const int tid  = threadIdx.x;
  const int w    = tid >> 6;
  const int lane = tid & 63;
  const int wr   = w >> 2;        // 0..1  (M)
  const int wc   = w & 3;         // 0..3  (N)
  const int lrow = lane & 15;
  const int kq   = lane >> 4;

  // staging: thread t covers source row (q*64 + t>>3), swizzled chunk
  // (t&7)^((t>>3)&7); dest is linear (HW: wave base + lane*16).
  const int srow = tid >> 3;                        // 0..63
  const int schk = ((tid & 7) ^ (srow & 7)) * 8;    // pre-swizzled source chunk
  const unsigned short* gA = A + (long)srow * lda + schk;
  const unsigned short* gB = B + (long)srow * ldb + schk;
  unsigned short* const stg = lds + w * 512;        // wave-uniform stage base part

  const int aoff  = (wr * 64 + lrow) * 64;          // + i*1024 per M-frag
  const int boff  = ((wc & 1) * 64 + lrow) * 64;    // + j*1024 per N-frag
  const int bunit = wc >> 1;                        // which B unit this wave reads
  const int pc0 = ((0 + kq) ^ (lrow & 7)) * 8;      // k-step 0 physical chunk
  const int pc1 = ((4 + kq) ^ (lrow & 7)) * 8;      // k-step 1 physical chunk

  // ---- prologue: stage units 0..4 = Blo(0),Bhi(0),A(0),Blo(1),Bhi(1) (in order)
  gload16(const_cast<unsigned short*>(gB) - 0,          stg);
  gload16(const_cast<unsigned short*>(gB) + (long)64 * ldb,  stg + 4096);
  gload16(const_cast<unsigned short*>(gB) + (long)128 * ldb, stg + 8192);
  gload16(const_cast<unsigned short*>(gB) + (long)192 * ldb, stg + 8192 + 4096);
  gload16(const_cast<unsigned short*>(gA),                   stg + 2 * 8192);
  gload16(const_cast<unsigned short*>(gA) + (long)64 * lda,  stg + 2 * 8192 + 4096);
  gload16(const_cast<unsigned short*>(gB) + 64,              stg + 3 * 8192);
  gload16(const_cast<unsigned short*>(gB) + 64 + (long)64 * ldb,  stg + 3 * 8192 + 4096);
  gload16(const_cast<unsigned short*>(gB) + 64 + (long)128 * ldb, stg + 4 * 8192);
  gload16(const_cast<unsigned short*>(gB) + 64 + (long)192 * ldb, stg + 4 * 8192 + 4096);
  VM4();            // units 0..2 (tile 0) landed; units 3,4 may be in flight
  BAR();

  for (int t = 0; t < NT; ++t) {
    const int r3 = 3 * (t & 1);
    const unsigned short* lA = lds + (r3 + 2) * 8192 + aoff;
    const unsigned short* lB = lds + (r3 + bunit) * 8192 + boff;

    bf16x8 bfr[4][2], af[2][2];
    // ---- phase 1 ----
#pragma unroll
    for (int j = 0; j < 4; ++j) {
      bfr[j][0] = *(const bf16x8*)(lB + j * 1024 + pc0);
      bfr[j][1] = *(const bf16x8*)(lB + j * 1024 + pc1);
    }
#pragma unroll
    for (int i = 0; i < 2; ++i) {
      af[i][0] = *(const bf16x8*)(lA + i * 1024 + pc0);
      af[i][1] = *(const bf16x8*)(lA + i * 1024 + pc1);
    }
    if (t + 1 < NT) {   // stage A(t+1) -> slot 3*((t+1)&1)+2
      const unsigned short* s = gA + (t + 1) * 64;
      unsigned short* d = stg + (3 * ((t + 1) & 1) + 2) * 8192;
      gload16(const_cast<unsigned short*>(s),                  d);
      gload16(const_cast<unsigned short*>(s) + (long)64 * lda, d + 4096);
    }
    BAR();
    LGKM0();
    __builtin_amdgcn_s_setprio(1);
#pragma unroll
    for (int i = 0; i < 2; ++i)
#pragma unroll
      for (int j = 0; j < 4; ++j) {
        acc[i][j] = __builtin_amdgcn_mfma_f32_16x16x32_bf16(af[i][0], bfr[j][0], acc[i][j], 0, 0, 0);
        acc[i][j] = __builtin_amdgcn_mfma_f32_16x16x32_bf16(af[i][1], bfr[j][1], acc[i][j], 0, 0, 0);
      }
    __builtin_amdgcn_s_setprio(0);
    BAR();

    // ---- phase 2 ----
#pragma unroll
    for (int i = 0; i < 2; ++i) {
      af[i][0] = *(const bf16x8*)(lA + (i + 2) * 1024 + pc0);
      af[i][1] = *(const bf16x8*)(lA + (i + 2) * 1024 + pc1);
    }
    if (t + 2 < NT) {   // stage Blo(t+2),Bhi(t+2) -> slots r3+0, r3+1
      const unsigned short* s = gB + (t + 2) * 64;
      unsigned short* d = stg + r3 * 8192;
      gload16(const_cast<unsigned short*>(s),                   d);
      gload16(const_cast<unsigned short*>(s) + (long)64 * ldb,  d + 4096);
      gload16(const_cast<unsigned short*>(s) + (long)128 * ldb, d + 8192);
      gload16(const_cast<unsigned short*>(s) + (long)192 * ldb, d + 8192 + 4096);
    }
    BAR();
    LGKM0();
    __builtin_amdgcn_s_setprio(1);
#pragma unroll
    for (int i = 0; i < 2; ++i)
#pragma unroll
      for (int j = 0; j < 4; ++j) {
        acc[i + 2][j] = __builtin_amdgcn_mfma_f32_16x16x32_bf16(af[i][0], bfr[j][0], acc[i + 2][j], 0, 0, 0);
        acc[i + 2][j] = __builtin_amdgcn_mfma_f32_16x16x32_bf16(af[i][1], bfr[j][1], acc[i + 2][j], 0, 0, 0);
      }
    __builtin_amdgcn_s_setprio(0);
    if (t == NT - 2) { VM0(); } else { VM4(); }   // boundary: tile t+1 landed
    BAR();
  }
}

// QKV projection: x[8192,1024] * W[1024,1024]^T + b, fused over Q/K/V.
// blockIdx.y = sel*4 + nb (nb = 256-wide col block). Q,K row-major bf16;
// V stored transposed per batch: Vt[b][d][m].
__global__ __launch_bounds__(512, 2) void gemm_qkv(
    const unsigned short* __restrict__ xh,
    const unsigned short* __restrict__ wh,
    const float* __restrict__ bq, const float* __restrict__ bk, const float* __restrict__ bv,
    unsigned short* __restrict__ Qh, unsigned short* __restrict__ Kh,
    unsigned short* __restrict__ Vth)
{
  __shared__ __align__(16) unsigned short lds[49152];
  const int Mblk = blockIdx.x * 128;
  const int sel  = blockIdx.y >> 2;   // 0=Q 1=K 2=V
  const int nb   = blockIdx.y & 3;    // 256-wide col block within 1024

  const unsigned short* A = xh + (long)Mblk * 1024;
  const unsigned short* B = wh + sel * 1048576 + (long)(nb * 256) * 1024;
  const float* bias = (sel == 0) ? bq : (sel == 1) ? bk : bv;

  f32x4 acc[4][4] = {};
  gemm_core(A, B, 1024, 1024, 16, lds, acc);

  const int lane = threadIdx.x & 63, w = threadIdx.x >> 6;
  const int wr = w >> 2, wc = w & 3;
  const int lrow = lane & 15, kq = lane >> 4;

#pragma unroll
  for (int i = 0; i < 4; ++i) {
#pragma unroll
    for (int j = 0; j < 4; ++j) {
      const int col = nb * 256 + wc * 64 + j * 16 + lrow;   // output feature d
      const float bsv = bias[col];
#pragma unroll
      for (int r = 0; r < 4; ++r) {
        const int tok = Mblk + wr * 64 + i * 16 + kq * 4 + r;  // token index
        const unsigned short h = f2bf(acc[i][j][r] + bsv);
        if (sel == 2) {
          Vth[(long)(tok >> 11) * 2097152 + (long)col * 2048 + (tok & 2047)] = h;
        } else if (sel == 0) {
          Qh[(long)tok * 1024 + col] = h;
        } else {
          Kh[(long)tok * 1024 + col] = h;
        }
      }
    }
  }
}

// Batched NT GEMM, fp32 out: C[z] = alpha * A[z] * B[z]^T  (tile 128x256)
__global__ __launch_bounds__(512, 2) void gemm_f32out(
    const unsigned short* __restrict__ A, const unsigned short* __restrict__ B,
    int lda, int ldb, int NT,
    long sA, long sB, float* __restrict__ C, int ldc, long sC, float alpha)
{
  __shared__ __align__(16) unsigned short lds[49152];
  const int Mblk = blockIdx.x * 128;
  const int Nblk = blockIdx.y * 256;
  const long z = blockIdx.z;
  const unsigned short* Ab = A + z * sA + (long)Mblk * lda;
  const unsigned short* Bb = B + z * sB + (long)Nblk * ldb;
  float* Cb = C + z * sC;

  f32x4 acc[4][4] = {};
  gemm_core(Ab, Bb, lda, ldb, NT, lds, acc);

  const int lane = threadIdx.x & 63, w = threadIdx.x >> 6;
  const int wr = w >> 2, wc = w & 3;
  const int lrow = lane & 15, kq = lane >> 4;
#pragma unroll
  for (int i = 0; i < 4; ++i)
#pragma unroll
    for (int j = 0; j < 4; ++j)
#pragma unroll
      for (int r = 0; r < 4; ++r) {
        const int row = Mblk + wr * 64 + i * 16 + kq * 4 + r;
        const int col = Nblk + wc * 64 + j * 16 + lrow;
        Cb[(long)row * ldc + col] = alpha * acc[i][j][r];
      }
}

// Row softmax over 2048 entries, in place (fp32) + bf16 copy for the PV GEMM.
__global__ __launch_bounds__(256) void softmax_rows(
    float* __restrict__ S, unsigned short* __restrict__ Ph)
{
  __shared__ float red[4];
  const long row = blockIdx.x;
  float* rp = S + row * 2048;
  const int t = threadIdx.x;

  float x[8];
  *(float4*)&x[0] = reinterpret_cast<const float4*>(rp)[t];
  *(float4*)&x[4] = reinterpret_cast<const float4*>(rp)[t + 256];

  float m = x[0];
#pragma unroll
  for (int i = 1; i < 8; ++i) m = fmaxf(m, x[i]);
  for (int o = 32; o; o >>= 1) m = fmaxf(m, __shfl_xor(m, o, 64));
  if ((t & 63) == 0) red[t >> 6] = m;
  __syncthreads();
  m = fmaxf(fmaxf(red[0], red[1]), fmaxf(red[2], red[3]));
  __syncthreads();

  float s = 0.f;
#pragma unroll
  for (int i = 0; i < 8; ++i) { x[i] = expf(x[i] - m); s += x[i]; }
  for (int o = 32; o; o >>= 1) s += __shfl_xor(s, o, 64);
  if ((t & 63) == 0) red[t >> 6] = s;
  __syncthreads();
  s = (red[0] + red[1]) + (red[2] + red[3]);
  const float inv = 1.0f / s;

#pragma unroll
  for (int i = 0; i < 8; ++i) x[i] *= inv;
  reinterpret_cast<float4*>(rp)[t]       = *(float4*)&x[0];
  reinterpret_cast<float4*>(rp)[t + 256] = *(float4*)&x[4];

  const long b0 = row * 2048 + t * 4;
#pragma unroll
  for (int k = 0; k < 4; ++k) Ph[b0 + k] = f2bf(x[k]);
  const long b1 = row * 2048 + 1024 + t * 4;
#pragma unroll
  for (int k = 0; k < 4; ++k) Ph[b1 + k] = f2bf(x[4 + k]);
}

__global__ __launch_bounds__(256) void to_bf16(
    const float* __restrict__ x, unsigned short* __restrict__ hi, int n4)
{
  int i = blockIdx.x * 256 + threadIdx.x;
  const int stride = gridDim.x * 256;
  for (; i < n4; i += stride) {
    const float4 v = reinterpret_cast<const float4*>(x)[i];
    ushort4 h;
    h.x = f2bf(v.x); h.y = f2bf(v.y); h.z = f2bf(v.z); h.w = f2bf(v.w);
    reinterpret_cast<ushort4*>(hi)[i] = h;
  }
}

extern "C" void kernel_launch(void* const* d_in, const int* in_sizes, int n_in,
                              void* d_out, int out_size, void* d_ws, size_t ws_size,
                              hipStream_t stream)
{
  const float* x  = (const float*)d_in[0];
  const float* Wq = (const float*)d_in[1];
  const float* bq = (const float*)d_in[2];
  const float* Wk = (const float*)d_in[3];
  const float* bk = (const float*)d_in[4];
  const float* Wv = (const float*)d_in[5];
  const float* bv = (const float*)d_in[6];

  float* out  = (float*)d_out;                 // [4,2048,1024]
  float* attn = (float*)d_out + 8388608;       // [4,2048,2048]

  unsigned short* ws  = (unsigned short*)d_ws;
  unsigned short* xh  = ws;                    //  8,388,608
  unsigned short* wh  = xh + 8388608;          //  3,145,728 (Wq|Wk|Wv)
  unsigned short* Qh  = wh + 3145728;          //  8,388,608
  unsigned short* Kh  = Qh + 8388608;          //  8,388,608
  unsigned short* Vth = Kh + 8388608;          //  8,388,608  Vt[b][d][m]
  unsigned short* Ph  = Vth + 8388608;         // 16,777,216  P bf16

  to_bf16<<<2048, 256, 0, stream>>>(x, xh, 2097152);
  to_bf16<<<512, 256, 0, stream>>>(Wq, wh, 262144);
  to_bf16<<<512, 256, 0, stream>>>(Wk, wh + 1048576, 262144);
  to_bf16<<<512, 256, 0, stream>>>(Wv, wh + 2097152, 262144);

  // Q,K,V projections (M=8192, N=3x1024, K=1024): 768 blocks = 3/CU exact
  gemm_qkv<<<dim3(64, 12), 512, 0, stream>>>(xh, wh, bq, bk, bv, Qh, Kh, Vth);

  // scores = Q K^T / 32 -> fp32 into d_out's attention slot: 512 blocks = 2/CU
  gemm_f32out<<<dim3(16, 8, 4), 512, 0, stream>>>(Qh, Kh, 1024, 1024, 16,
      2097152L, 2097152L, attn, 2048, 4194304L, 0.03125f);

  // softmax rows in place + emit P bf16
  softmax_rows<<<8192, 256, 0, stream>>>(attn, Ph);

  // out = P * Vt^T (K=2048 -> NT=32): 256 blocks = 1/CU
  gemm_f32out<<<dim3(16, 4, 4), 512, 0, stream>>>(Ph, Vth, 2048, 2048, 32,
      4194304L, 2097152L, out, 1024, 2097152L, 1.0f);
}